// Round 9
// baseline (125.344 us; speedup 1.0000x reference)
//
#include <hip/hip_runtime.h>
#include <stdint.h>

// Problem constants (from the reference)
constexpr int Tdim = 4096;   // time / input width
constexpr int Ndim = 4096;   // neurons
constexpr int Bdim = 1024;   // batch
constexpr int NB   = 16;     // address bits
constexpr int WPN  = 2115;   // words per neuron = ceil(65536 / 31)

// ---------------------------------------------------------------------------
// Per-wave layout probe: int64-on-device arrays (values < 2^31) have zero
// high halves at every odd int32 slot. 64 probes via ballot; false positive
// <= 2^-64. Returns the int32-index multiplier (2 = int64, 1 = int32).
// ---------------------------------------------------------------------------
__device__ __forceinline__ int probe_stride(const int* __restrict__ p) {
    const int l = threadIdx.x & 63;
    return (__ballot(p[2 * l + 1] == 0) == ~0ull) ? 2 : 1;
}

// ---------------------------------------------------------------------------
// Kernel 1: pack x (B x T of 0/1) into bit-planes:
//   xT[bg * T + t] = uint32 whose bit bl = x[(bg*32 + bl) * T + t]
// ---------------------------------------------------------------------------
__global__ __launch_bounds__(256) void pack_kernel(const int* __restrict__ x,
                                                   uint32_t* __restrict__ xT) {
    const int sx = probe_stride(x);
    const int t  = blockIdx.x * 256 + threadIdx.x;
    const int bg = blockIdx.y;
    uint32_t w = 0;
#pragma unroll
    for (int bl = 0; bl < 32; ++bl) {
        const size_t idx = ((size_t)(bg * 32 + bl) * Tdim + t) * sx;
        w |= (uint32_t)(x[idx] & 1) << bl;
    }
    xT[(size_t)bg * Tdim + t] = w;
}

// ---------------------------------------------------------------------------
// Kernel 2 v4 (stream-table-to-LDS): block = 256 thr = 2 neurons x ALL 1024
// batches; grid 2048. The table is read ONCE, fully COALESCED (sequential
// uint2 loads -> stream BW), then all 1024 lookups/row are LDS reads.
// This converts the r5-r8 bottleneck (random 64B HBM demand-misses at
// ~1.5 TB/s MLP-limited) into streaming at ~5-6 TB/s.
//
// Phase A: stream rows n0,n0+1 (4230 words) -> rowbuf (low32 compacted);
//          gather 2x32x16 conn-bit matrix from L2-resident xT -> bits.
// Phase B: per (n,bg): addr from bits[n][bg][0..15] (b128-friendly) ->
//          random LDS read rowbuf[wi] -> ballot-pack 2-bit vals.
// Phase C: store; XCD-swizzled blockIdx so the 8 sibling blocks sharing
//          each 64-B out line run on ONE XCD (L2 assembles full lines).
// ---------------------------------------------------------------------------
__global__ __launch_bounds__(256) void row_kernel(const uint32_t* __restrict__ xT,
                                                  const int* __restrict__ conn,
                                                  const int* __restrict__ mem,
                                                  int* __restrict__ out) {
    const int sc = probe_stride(conn);
    const int sm = probe_stride(mem);

    // swizzle: blocks bx = g*8 + r for r=0..7 have launch idx i = g + 256*r
    // -> i % 8 == g % 8: all 8 siblings of out-line group g on the same XCD.
    const int i  = blockIdx.x;
    const int bx = (i & 255) * 8 + (i >> 8);   // [0, 2048)
    const int n0 = bx * 2;

    const int tid = threadIdx.x;

    __shared__ uint32_t rowbuf[2 * WPN];       // 16.9 KB: 2 compacted rows
    __shared__ uint32_t bits[2 * 32 * 16];     // [n_l][bg][j] 4 KB
    __shared__ uint64_t omask[2][16][2];       // [n_l][b>>6][plane] 0.5 KB

    // Phase A1: stream 4230 table words, coalesced (sequential lines)
    const size_t base = (size_t)n0 * WPN;
    if (sm == 2) {                             // int64 layout: uint2, keep .x
        const uint2* m2 = (const uint2*)mem;
#pragma unroll
        for (int k = 0; k < 17; ++k) {
            const int idx = k * 256 + tid;
            if (idx < 2 * WPN) rowbuf[idx] = m2[base + idx].x;
        }
    } else {                                   // int32 layout
        const uint32_t* m1 = (const uint32_t*)mem;
#pragma unroll
        for (int k = 0; k < 17; ++k) {
            const int idx = k * 256 + tid;
            if (idx < 2 * WPN) rowbuf[idx] = m1[base + idx];
        }
    }

    // Phase A2: conn-bit matrix gather (xT is 512 KB, L2-resident)
#pragma unroll
    for (int k = 0; k < 4; ++k) {
        const int idx = k * 256 + tid;         // [0,1024)
        const int n_l = idx >> 9;
        const int bg  = (idx >> 4) & 31;
        const int j   = idx & 15;
        const int c   = conn[((n0 + n_l) * NB + j) * sc];
        bits[idx] = xT[(size_t)bg * Tdim + c];
    }
    __syncthreads();                           // single latency exposure

    // Phase B: 2048 lookups, all from LDS
    const int w   = tid >> 6;                  // wave 0..3
    const int l   = tid & 63;
    const int bit = l & 31;
    const int hi  = l >> 5;
#pragma unroll
    for (int n_l = 0; n_l < 2; ++n_l) {
        const uint32_t* myrow = &rowbuf[n_l * WPN];
        const uint32_t* myb   = &bits[n_l * 512];
#pragma unroll
        for (int it = 0; it < 4; ++it) {
            const int bg = w * 8 + it * 2 + hi;      // b = bg*32 + bit
            const uint32_t* bp = &myb[bg * 16];      // 16 words, 64B-aligned
            uint32_t addr = 0;
#pragma unroll
            for (int j = 0; j < 16; ++j)             // conn[0] = MSB
                addr = (addr << 1) | ((bp[j] >> bit) & 1u);
            const uint32_t wi = addr / 31u;          // magic-mul
            const uint32_t sh = (addr - wi * 31u) * 2u;   // 0..60
            // uint64 promote: sh>=32 -> 0, matching the int64 reference
            const uint32_t v = (uint32_t)(((uint64_t)myrow[wi] >> sh) & 3ull);
            const uint64_t b0 = __ballot((v & 1u) != 0u);
            const uint64_t b1 = __ballot((v & 2u) != 0u);
            if (l == 0) {                            // b>>6 = w*4+it
                omask[n_l][w * 4 + it][0] = b0;
                omask[n_l][w * 4 + it][1] = b1;
            }
        }
    }
    __syncthreads();

    // Phase C: 2048 int32 stores (8 B per out line; XCD swizzle -> L2 merge)
#pragma unroll
    for (int k = 0; k < 8; ++k) {
        const int t2  = k * 256 + tid;         // [0,2048)
        const int n_l = t2 & 1;
        const int b   = t2 >> 1;               // [0,1024)
        const uint64_t m0 = omask[n_l][b >> 6][0];
        const uint64_t m1 = omask[n_l][b >> 6][1];
        const int s = b & 63;
        const int v = (int)((m0 >> s) & 1ull) | ((int)((m1 >> s) & 1ull) << 1);
        out[(size_t)b * Ndim + n0 + n_l] = v;
    }
}

// ---------------------------------------------------------------------------
// Fallback (only if ws_size < 512 KB): direct per-(b,n) gather. Correct, slower.
// ---------------------------------------------------------------------------
__global__ __launch_bounds__(256) void direct_kernel(const int* __restrict__ x,
                                                     const int* __restrict__ conn,
                                                     const int* __restrict__ mem,
                                                     int* __restrict__ out) {
    const int sx = probe_stride(x);
    const int sc = probe_stride(conn);
    const int sm = probe_stride(mem);
    const int n  = blockIdx.x * 256 + threadIdx.x;   // lane = n -> coalesced store
    const int b  = blockIdx.y;
    const int* cp = conn + (size_t)n * NB * sc;
    const int* xr = x + (size_t)b * Tdim * sx;
    uint32_t addr = 0;
#pragma unroll
    for (int j = 0; j < 16; ++j)
        addr = (addr << 1) | (uint32_t)(xr[(size_t)cp[j * sc] * sx] & 1);
    const uint32_t wi = addr / 31u;
    const uint32_t sh = (addr - wi * 31u) * 2u;
    const uint64_t wd = (uint32_t)mem[((size_t)n * WPN + wi) * sm];
    out[(size_t)b * Ndim + n] = (int)((wd >> sh) & 3u);
}

// ---------------------------------------------------------------------------
extern "C" void kernel_launch(void* const* d_in, const int* in_sizes, int n_in,
                              void* d_out, int out_size, void* d_ws, size_t ws_size,
                              hipStream_t stream) {
    const int* x    = (const int*)d_in[0];       // (B, T) 0/1
    const int* conn = (const int*)d_in[1];       // (N, 16) indices < T
    const int* mem  = (const int*)d_in[2];       // (N, WPN), values < 2^31
    int*       out  = (int*)d_out;               // (B, N), read back as np.int32
    uint32_t*  xT   = (uint32_t*)d_ws;           // (B/32, T) bit-planes, 512 KB

    const size_t need = (size_t)(Bdim / 32) * Tdim * sizeof(uint32_t);
    if (ws_size >= need) {
        dim3 g1(Tdim / 256, Bdim / 32);          // 16 x 32 = 512 blocks
        pack_kernel<<<g1, 256, 0, stream>>>(x, xT);
        row_kernel<<<Ndim / 2, 256, 0, stream>>>(xT, conn, mem, out);
    } else {
        dim3 g3(Ndim / 256, Bdim);               // 16 x 1024 blocks
        direct_kernel<<<g3, 256, 0, stream>>>(x, conn, mem, out);
    }
}

// Round 10
// 106.615 us; speedup vs baseline: 1.1757x; 1.1757x over previous
//
#include <hip/hip_runtime.h>
#include <stdint.h>

// Problem constants (from the reference)
constexpr int Tdim = 4096;   // time / input width
constexpr int Ndim = 4096;   // neurons
constexpr int Bdim = 1024;   // batch
constexpr int NB   = 16;     // address bits
constexpr int WPN  = 2115;   // words per neuron = ceil(65536 / 31)

// ---------------------------------------------------------------------------
// Per-wave layout probe: int64-on-device arrays (values < 2^31) have zero
// high halves at every odd int32 slot. 64 probes via ballot; false positive
// <= 2^-64. Returns the int32-index multiplier (2 = int64, 1 = int32).
// ---------------------------------------------------------------------------
__device__ __forceinline__ int probe_stride(const int* __restrict__ p) {
    const int l = threadIdx.x & 63;
    return (__ballot(p[2 * l + 1] == 0) == ~0ull) ? 2 : 1;
}

// ---------------------------------------------------------------------------
// Kernel 1: pack x (B x T of 0/1) into bit-planes:
//   xT[bg * T + t] = uint32 whose bit bl = x[(bg*32 + bl) * T + t]
// ---------------------------------------------------------------------------
__global__ __launch_bounds__(256) void pack_kernel(const int* __restrict__ x,
                                                   uint32_t* __restrict__ xT) {
    const int sx = probe_stride(x);
    const int t  = blockIdx.x * 256 + threadIdx.x;
    const int bg = blockIdx.y;
    uint32_t w = 0;
#pragma unroll
    for (int bl = 0; bl < 32; ++bl) {
        const size_t idx = ((size_t)(bg * 32 + bl) * Tdim + t) * sx;
        w |= (uint32_t)(x[idx] & 1) << bl;
    }
    xT[(size_t)bg * Tdim + t] = w;
}

// ---------------------------------------------------------------------------
// Kernel 2 v5 (stream + packed-emit): block = 256 thr = 2 neurons x ALL 1024
// batches; grid = N/2 = 2048 blocks (natural order -> sequential table rows).
//
// Phase A1: stream rows n0,n0+1 (2x2115 words) -> rowbuf, coalesced.
// Phase A2: gather 2x32x16 conn-bit matrix from L2-resident xT -> bits.
// Phase B : per (n,bg): 4 x ds_read_b128 give the 16 addr words; 16-bit addr
//           -> random LDS read rowbuf[wi] -> 2-bit val, ballot-packed.
// Phase C : 512 B contiguous store of the 64 packed uint64 masks -> pmask.
//           (r9 lesson: 8 B/line scattered stores to `out` cost 66 MB of
//           partial-line HBM writes; packed emit makes writes negligible.)
// ---------------------------------------------------------------------------
__global__ __launch_bounds__(256) void row_kernel(const uint32_t* __restrict__ xT,
                                                  const int* __restrict__ conn,
                                                  const int* __restrict__ mem,
                                                  uint64_t* __restrict__ pmask) {
    const int sc = probe_stride(conn);
    const int sm = probe_stride(mem);

    const int n0  = blockIdx.x * 2;
    const int tid = threadIdx.x;

    __shared__ uint32_t rowbuf[2 * WPN];       // 16.9 KB: 2 compacted rows
    __shared__ uint4    bits4[2 * 32 * 4];     // [n_l][bg][j/4] 4 KB (16B align)
    __shared__ uint64_t omask[2 * 16 * 2];     // [n_l][b>>6][plane] 0.5 KB
    uint32_t* bits = (uint32_t*)bits4;

    // Phase A1: stream 4230 table words, coalesced (sequential lines)
    const size_t base = (size_t)n0 * WPN;
    if (sm == 2) {                             // int64 layout: uint2, keep .x
        const uint2* m2 = (const uint2*)mem;
#pragma unroll
        for (int k = 0; k < 17; ++k) {
            const int idx = k * 256 + tid;
            if (idx < 2 * WPN) rowbuf[idx] = m2[base + idx].x;
        }
    } else {                                   // int32 layout
        const uint32_t* m1 = (const uint32_t*)mem;
#pragma unroll
        for (int k = 0; k < 17; ++k) {
            const int idx = k * 256 + tid;
            if (idx < 2 * WPN) rowbuf[idx] = m1[base + idx];
        }
    }

    // Phase A2: conn-bit matrix gather (xT is 512 KB, L2-resident)
#pragma unroll
    for (int k = 0; k < 4; ++k) {
        const int idx = k * 256 + tid;         // [0,1024)
        const int n_l = idx >> 9;
        const int bg  = (idx >> 4) & 31;
        const int j   = idx & 15;
        const int c   = conn[((n0 + n_l) * NB + j) * sc];
        bits[idx] = xT[(size_t)bg * Tdim + c];
    }
    __syncthreads();                           // single latency exposure

    // Phase B: 2048 lookups, all from LDS
    const int w   = tid >> 6;                  // wave 0..3
    const int l   = tid & 63;
    const int bit = l & 31;
    const int hi  = l >> 5;
#pragma unroll
    for (int n_l = 0; n_l < 2; ++n_l) {
        const uint32_t* myrow = &rowbuf[n_l * WPN];
#pragma unroll
        for (int it = 0; it < 4; ++it) {
            const int bg = w * 8 + it * 2 + hi;      // b = bg*32 + bit
            const uint4* bp4 = &bits4[n_l * 128 + bg * 4];
            uint32_t wv[16];
#pragma unroll
            for (int q = 0; q < 4; ++q) {            // 4 x ds_read_b128
                const uint4 v4 = bp4[q];
                wv[q * 4 + 0] = v4.x; wv[q * 4 + 1] = v4.y;
                wv[q * 4 + 2] = v4.z; wv[q * 4 + 3] = v4.w;
            }
            uint32_t addr = 0;
#pragma unroll
            for (int j = 0; j < 16; ++j)             // conn[0] = MSB
                addr = (addr << 1) | ((wv[j] >> bit) & 1u);
            const uint32_t wi = addr / 31u;          // magic-mul
            const uint32_t sh = (addr - wi * 31u) * 2u;   // 0..60
            // uint64 promote: sh>=32 -> 0, matching the int64 reference
            const uint32_t v = (uint32_t)(((uint64_t)myrow[wi] >> sh) & 3ull);
            const uint64_t b0 = __ballot((v & 1u) != 0u);
            const uint64_t b1 = __ballot((v & 2u) != 0u);
            if (l == 0) {                            // b>>6 = w*4+it
                omask[n_l * 32 + (w * 4 + it) * 2 + 0] = b0;
                omask[n_l * 32 + (w * 4 + it) * 2 + 1] = b1;
            }
        }
    }
    __syncthreads();

    // Phase C: 64 x uint64 = 512 B contiguous packed emit
    if (tid < 64) pmask[(size_t)n0 * 32 + tid] = omask[tid];
}

// ---------------------------------------------------------------------------
// Kernel 3 (unpack): block = 16 neurons x 1024 batches; grid = N/16 = 256.
// Reads 4 KB of packed masks, writes 64 KB of out as FULL 64-B lines
// (wave = 4 batches x 16 neurons). Pure streaming.
// ---------------------------------------------------------------------------
__global__ __launch_bounds__(256) void unpack_kernel(const uint64_t* __restrict__ pmask,
                                                     int* __restrict__ out) {
    const int n0  = blockIdx.x * 16;
    const int tid = threadIdx.x;

    __shared__ uint64_t m[16 * 32];            // [n_l][p*2+plane] 4 KB
#pragma unroll
    for (int k = 0; k < 2; ++k) {
        const int idx = k * 256 + tid;
        m[idx] = pmask[(size_t)n0 * 32 + idx];
    }
    __syncthreads();

    const int nl = tid & 15;                   // local neuron column
    const int b0 = tid >> 4;                   // 0..15
#pragma unroll
    for (int q = 0; q < 64; ++q) {
        const int b = q * 16 + b0;             // [0,1024)
        const int p = b >> 6;
        const int s = b & 63;
        const uint64_t m0 = m[nl * 32 + p * 2 + 0];
        const uint64_t m1 = m[nl * 32 + p * 2 + 1];
        const int v = (int)((m0 >> s) & 1ull) | ((int)((m1 >> s) & 1ull) << 1);
        out[(size_t)b * Ndim + n0 + nl] = v;
    }
}

// ---------------------------------------------------------------------------
// Fallback (only if ws_size too small): direct per-(b,n) gather. Correct, slower.
// ---------------------------------------------------------------------------
__global__ __launch_bounds__(256) void direct_kernel(const int* __restrict__ x,
                                                     const int* __restrict__ conn,
                                                     const int* __restrict__ mem,
                                                     int* __restrict__ out) {
    const int sx = probe_stride(x);
    const int sc = probe_stride(conn);
    const int sm = probe_stride(mem);
    const int n  = blockIdx.x * 256 + threadIdx.x;   // lane = n -> coalesced store
    const int b  = blockIdx.y;
    const int* cp = conn + (size_t)n * NB * sc;
    const int* xr = x + (size_t)b * Tdim * sx;
    uint32_t addr = 0;
#pragma unroll
    for (int j = 0; j < 16; ++j)
        addr = (addr << 1) | (uint32_t)(xr[(size_t)cp[j * sc] * sx] & 1);
    const uint32_t wi = addr / 31u;
    const uint32_t sh = (addr - wi * 31u) * 2u;
    const uint64_t wd = (uint32_t)mem[((size_t)n * WPN + wi) * sm];
    out[(size_t)b * Ndim + n] = (int)((wd >> sh) & 3u);
}

// ---------------------------------------------------------------------------
extern "C" void kernel_launch(void* const* d_in, const int* in_sizes, int n_in,
                              void* d_out, int out_size, void* d_ws, size_t ws_size,
                              hipStream_t stream) {
    const int* x    = (const int*)d_in[0];       // (B, T) 0/1
    const int* conn = (const int*)d_in[1];       // (N, 16) indices < T
    const int* mem  = (const int*)d_in[2];       // (N, WPN), values < 2^31
    int*       out  = (int*)d_out;               // (B, N), read back as np.int32
    uint32_t*  xT   = (uint32_t*)d_ws;           // bit-planes, 512 KB
    uint64_t*  pmask = (uint64_t*)((char*)d_ws + (size_t)(Bdim / 32) * Tdim * 4);

    const size_t need = (size_t)(Bdim / 32) * Tdim * 4 + (size_t)Ndim * 32 * 8;
    if (ws_size >= need) {
        dim3 g1(Tdim / 256, Bdim / 32);          // 16 x 32 = 512 blocks
        pack_kernel<<<g1, 256, 0, stream>>>(x, xT);
        row_kernel<<<Ndim / 2, 256, 0, stream>>>(xT, conn, mem, pmask);
        unpack_kernel<<<Ndim / 16, 256, 0, stream>>>(pmask, out);
    } else {
        dim3 g3(Ndim / 256, Bdim);               // 16 x 1024 blocks
        direct_kernel<<<g3, 256, 0, stream>>>(x, conn, mem, out);
    }
}